// Round 3
// baseline (300.320 us; speedup 1.0000x reference)
//
#include <hip/hip_runtime.h>
#include <cmath>

constexpr int BB = 4, CC = 64, HH = 256, WW = 256;
constexpr int WP = 258;   // padded width: cols -1..256 stored at col+1
constexpr int C2R = 257;  // c2 rows -1..255 stored at r+1

typedef short short8 __attribute__((ext_vector_type(8)));
typedef float f32x4 __attribute__((ext_vector_type(4)));
#define MFMA_BF16 __builtin_amdgcn_mfma_f32_16x16x32_bf16

union U16x8 { uint4 v; unsigned short h[8]; };

__device__ inline unsigned short f2bf(float f) {
  unsigned u = __builtin_bit_cast(unsigned, f);
  u += 0x7fffu + ((u >> 16) & 1u);
  return (unsigned short)(u >> 16);
}
__device__ inline float bf2f(unsigned short h) {
  unsigned u = ((unsigned)h) << 16;
  return __builtin_bit_cast(float, u);
}

// ---------------------------------------------------------------------------
// k_pack: block (y, b). NCHW fp32 -> col-padded NHWC bf16 (width 258, zero
// cols at 0 and 257), fused channel-max -> s.
// ---------------------------------------------------------------------------
__global__ __launch_bounds__(256) void k_pack(const float* __restrict__ x,
                                              float* __restrict__ s,
                                              unsigned short* __restrict__ xn) {
  __shared__ float tile[CC * WW];
  const int t = threadIdx.x, y = blockIdx.x, b = blockIdx.y;
  const float* base = x + (size_t)b * CC * HH * WW + y * WW + t;
  float m = -1e30f;
#pragma unroll 8
  for (int c = 0; c < CC; ++c) {
    float v = base[(size_t)c * HH * WW];
    tile[c * WW + t] = v;
    m = fmaxf(m, v);
  }
  s[(b * HH + y) * WW + t] = 25.0f / fminf(fmaxf(m, 1.0f), 50.0f);
  uint4* xn4 = (uint4*)xn;
  if (t < 16) {  // zero col pads
    int col = (t >> 3) ? (WP - 1) : 0, c8 = t & 7;
    xn4[(((size_t)(b * HH + y) * WP + col) * CC + c8 * 8) >> 3] =
        make_uint4(0, 0, 0, 0);
  }
  __syncthreads();
#pragma unroll
  for (int g = 0; g < 8; ++g) {
    int px = g * 32 + (t >> 3), c8 = t & 7;
    U16x8 r;
#pragma unroll
    for (int j = 0; j < 8; ++j) r.h[j] = f2bf(tile[(c8 * 8 + j) * WW + px]);
    xn4[(((size_t)(b * HH + y) * WP + px + 1) * CC + c8 * 8) >> 3] = r.v;
  }
}

// ---------------------------------------------------------------------------
// k_wpack: W [64][64][3][3] fp32 -> bf16 fragments Wp[tap][mtile][kc][lane][8]
// value = W[o = mtile*16 + (lane&15)][cin = kc*32 + (lane>>4)*8 + j][ky][kx]
// (works as A-operand with m=lane&15 and as B-operand with n=lane&15)
// ---------------------------------------------------------------------------
__global__ __launch_bounds__(256) void k_wpack(const float* __restrict__ Wt,
                                               unsigned short* __restrict__ Wp) {
  int gid = blockIdx.x * 256 + threadIdx.x;  // 4608 total
  int lane = gid & 63, kc = (gid >> 6) & 1, mt = (gid >> 7) & 3, tap = gid >> 9;
  int o = mt * 16 + (lane & 15);
  int kb = kc * 32 + (lane >> 4) * 8;
  int ky = tap / 3, kx = tap % 3;
  U16x8 r;
#pragma unroll
  for (int j = 0; j < 8; ++j)
    r.h[j] = f2bf(Wt[o * 576 + (kb + j) * 9 + ky * 3 + kx]);
  ((uint4*)Wp)[gid] = r.v;
}

// ---------------------------------------------------------------------------
// k_warp: x2 row r = w0*xn[a0] + w1*xn[a1] (vertical bilinear), col-padded
// NHWC bf16 like xn. Grid (HH, BB).
// ---------------------------------------------------------------------------
__global__ __launch_bounds__(256) void k_warp(const unsigned short* __restrict__ xn,
                                              const float* __restrict__ s,
                                              unsigned short* __restrict__ x2) {
  const int t = threadIdx.x, r = blockIdx.x, b = blockIdx.y;
  const uint4* xn4 = (const uint4*)xn;
  uint4* x24 = (uint4*)x2;
  if (t < 16) {  // zero col pads
    int col = (t >> 3) ? (WP - 1) : 0, c8 = t & 7;
    x24[(((size_t)(b * HH + r) * WP + col) * CC + c8 * 8) >> 3] =
        make_uint4(0, 0, 0, 0);
  }
#pragma unroll
  for (int g = 0; g < 8; ++g) {
    int px = g * 32 + (t >> 3), c8 = t & 7;
    float sv = s[(b * HH + r) * WW + px];
    float ys = (float)r - sv;
    float fy = floorf(ys);
    float wfr = ys - fy;
    int i0 = (int)fy;
    float w0 = (i0 >= 0 && i0 < HH) ? 1.0f - wfr : 0.0f;
    float w1 = (i0 + 1 >= 0 && i0 + 1 < HH) ? wfr : 0.0f;
    int a0 = min(max(i0, 0), HH - 1), a1 = min(max(i0 + 1, 0), HH - 1);
    U16x8 u0, u1, rr;
    u0.v = xn4[(((size_t)(b * HH + a0) * WP + px + 1) * CC + c8 * 8) >> 3];
    u1.v = xn4[(((size_t)(b * HH + a1) * WP + px + 1) * CC + c8 * 8) >> 3];
#pragma unroll
    for (int k = 0; k < 8; ++k)
      rr.h[k] = f2bf(w0 * bf2f(u0.h[k]) + w1 * bf2f(u1.h[k]));
    x24[(((size_t)(b * HH + r) * WP + px + 1) * CC + c8 * 8) >> 3] = rr.v;
  }
}

// ---------------------------------------------------------------------------
// k_lower: c2 row r = blockIdx.x-1. Pure dense conv3x3 over x2 (global-read
// fragments, no LDS). D = W x X (ch-major). Store c2 bf16 NHWC.
// ---------------------------------------------------------------------------
__global__ __launch_bounds__(256, 2) void k_lower(const unsigned short* __restrict__ x2,
                                                  const unsigned short* __restrict__ Wp,
                                                  unsigned short* __restrict__ c2) {
  const int t = threadIdx.x;
  const int r = (int)blockIdx.x - 1;
  const int b = blockIdx.y;
  const int lane = t & 63, w = t >> 6;
  const int p = w >> 1, h = w & 1;
  const int quad = lane >> 4, l15 = lane & 15;

  short8 wf[9][2][2];
  const uint4* wp4 = (const uint4*)Wp;
#pragma unroll
  for (int tap = 0; tap < 9; ++tap)
#pragma unroll
    for (int ct = 0; ct < 2; ++ct)
#pragma unroll
      for (int kc = 0; kc < 2; ++kc)
        wf[tap][ct][kc] = __builtin_bit_cast(
            short8, wp4[((tap * 4 + (2 * p + ct)) * 2 + kc) * 64 + lane]);

  const uint4* xb = (const uint4*)x2;
  bool rv[3];
  size_t rbase[3];
#pragma unroll
  for (int ky = 0; ky < 3; ++ky) {
    int xrow = r - 1 + ky;
    rv[ky] = (xrow >= 0 && xrow < HH);
    rbase[ky] = (size_t)(b * HH + min(max(xrow, 0), HH - 1)) * WP * 8;
  }

#pragma unroll 1
  for (int pt = 0; pt < 8; ++pt) {
    int pxb = h * 128 + pt * 16;
    f32x4 acc0 = {0.f, 0.f, 0.f, 0.f}, acc1 = {0.f, 0.f, 0.f, 0.f};
#pragma unroll
    for (int ky = 0; ky < 3; ++ky) {
      if (!rv[ky]) continue;  // wave-uniform
#pragma unroll
      for (int kx = 0; kx < 3; ++kx) {
        int colp = pxb + l15 + kx;  // padded col index, in [0,257]
#pragma unroll
        for (int kc = 0; kc < 2; ++kc) {
          short8 a = __builtin_bit_cast(
              short8, xb[rbase[ky] + (size_t)colp * 8 + kc * 4 + quad]);
          acc0 = MFMA_BF16(wf[ky * 3 + kx][0][kc], a, acc0, 0, 0, 0);
          acc1 = MFMA_BF16(wf[ky * 3 + kx][1][kc], a, acc1, 0, 0, 0);
        }
      }
    }
    int px = pxb + l15;
#pragma unroll
    for (int ct = 0; ct < 2; ++ct) {
      f32x4 A = ct ? acc1 : acc0;
      int ch = (2 * p + ct) * 16 + quad * 4;
      unsigned short h0 = f2bf(A[0]), h1 = f2bf(A[1]), h2 = f2bf(A[2]), h3 = f2bf(A[3]);
      uint2 val = make_uint2((unsigned)h0 | ((unsigned)h1 << 16),
                             (unsigned)h2 | ((unsigned)h3 << 16));
      *(uint2*)(c2 + (((size_t)(b * C2R + (r + 1)) * WW + px) * CC + ch)) = val;
    }
  }
}

// ---------------------------------------------------------------------------
// k_final: dense conv3x3 over xn (global-read fragments, no LDS),
// D = X x W (px-major), + c2 vertical resample + min -> out NCHW fp32.
// ---------------------------------------------------------------------------
__global__ __launch_bounds__(256, 2) void k_final(const unsigned short* __restrict__ xn,
                                                  const unsigned short* __restrict__ Wp,
                                                  const float* __restrict__ s,
                                                  const unsigned short* __restrict__ c2,
                                                  float* __restrict__ out) {
  const int t = threadIdx.x;
  const int y = blockIdx.x;
  const int b = blockIdx.y;
  const int lane = t & 63, w = t >> 6;
  const int p = w >> 1, h = w & 1;
  const int quad = lane >> 4, l15 = lane & 15;

  short8 wf[9][2][2];
  const uint4* wp4 = (const uint4*)Wp;
#pragma unroll
  for (int tap = 0; tap < 9; ++tap)
#pragma unroll
    for (int ct = 0; ct < 2; ++ct)
#pragma unroll
      for (int kc = 0; kc < 2; ++kc)
        wf[tap][ct][kc] = __builtin_bit_cast(
            short8, wp4[((tap * 4 + (2 * p + ct)) * 2 + kc) * 64 + lane]);

  const uint4* xb = (const uint4*)xn;
  bool rv[3];
  size_t rbase[3];
#pragma unroll
  for (int ky = 0; ky < 3; ++ky) {
    int xrow = y - 1 + ky;
    rv[ky] = (xrow >= 0 && xrow < HH);
    rbase[ky] = (size_t)(b * HH + min(max(xrow, 0), HH - 1)) * WP * 8;
  }

#pragma unroll 1
  for (int pt = 0; pt < 8; ++pt) {
    int pxb = h * 128 + pt * 16;
    f32x4 acc0 = {0.f, 0.f, 0.f, 0.f}, acc1 = {0.f, 0.f, 0.f, 0.f};
#pragma unroll
    for (int ky = 0; ky < 3; ++ky) {
      if (!rv[ky]) continue;  // wave-uniform
#pragma unroll
      for (int kx = 0; kx < 3; ++kx) {
        int colp = pxb + l15 + kx;
#pragma unroll
        for (int kc = 0; kc < 2; ++kc) {
          short8 a = __builtin_bit_cast(
              short8, xb[rbase[ky] + (size_t)colp * 8 + kc * 4 + quad]);
          acc0 = MFMA_BF16(a, wf[ky * 3 + kx][0][kc], acc0, 0, 0, 0);
          acc1 = MFMA_BF16(a, wf[ky * 3 + kx][1][kc], acc1, 0, 0, 0);
        }
      }
    }
    // epilogue: sample c2 at rows floor(y-s)+1, +2 (stored +1); min; store
    int px0 = pxb + quad * 4;
    f32x4 sv4 = *(const f32x4*)(s + (b * HH + y) * WW + px0);
    float lw0[4], lw1[4];
    int a0i[4], a1i[4];
#pragma unroll
    for (int rr = 0; rr < 4; ++rr) {
      float ys = (float)y - sv4[rr];
      float fy = floorf(ys);
      float wfr = ys - fy;
      int i0 = (int)fy;
      lw0[rr] = (i0 + 1 >= 0 && i0 + 1 <= HH) ? 1.0f - wfr : 0.0f;
      lw1[rr] = (i0 + 2 >= 0 && i0 + 2 <= HH) ? wfr : 0.0f;
      a0i[rr] = min(max(i0 + 1, 0), HH);
      a1i[rr] = min(max(i0 + 2, 0), HH);
    }
#pragma unroll
    for (int ct = 0; ct < 2; ++ct) {
      f32x4 A = ct ? acc1 : acc0;
      int ch = (2 * p + ct) * 16 + l15;
      f32x4 res;
#pragma unroll
      for (int rr = 0; rr < 4; ++rr) {
        int px = px0 + rr;
        float v0 = bf2f(c2[((size_t)(b * C2R + a0i[rr]) * WW + px) * CC + ch]);
        float v1 = bf2f(c2[((size_t)(b * C2R + a1i[rr]) * WW + px) * CC + ch]);
        res[rr] = fminf(A[rr], lw0[rr] * v0 + lw1[rr] * v1);
      }
      *(f32x4*)(out + ((size_t)(b * CC + ch) * HH + y) * WW + px0) = res;
    }
  }
}

// ---------------------------------------------------------------------------
extern "C" void kernel_launch(void* const* d_in, const int* in_sizes, int n_in,
                              void* d_out, int out_size, void* d_ws, size_t ws_size,
                              hipStream_t stream) {
  const float* x = (const float*)d_in[0];
  const float* Wt = (const float*)d_in[1];
  float* out = (float*)d_out;

  char* ws = (char*)d_ws;
  float* s = (float*)ws;                                   //   1,048,576 B
  unsigned short* Wp = (unsigned short*)(ws + 1048576);    //      73,728 B
  unsigned short* xn = (unsigned short*)(ws + 1122304);    //  33,816,576 B
  unsigned short* x2 = (unsigned short*)(ws + 34938880);   //  33,816,576 B
  unsigned short* c2 = (unsigned short*)(ws + 68755456);   //  33,685,504 B
                                                           // total 102.4 MB
  k_pack<<<dim3(HH, BB), 256, 0, stream>>>(x, s, xn);
  k_wpack<<<dim3(18), 256, 0, stream>>>(Wt, Wp);
  k_warp<<<dim3(HH, BB), 256, 0, stream>>>(xn, s, x2);
  k_lower<<<dim3(C2R, BB), 256, 0, stream>>>(x2, Wp, c2);
  k_final<<<dim3(HH, BB), 256, 0, stream>>>(xn, Wp, s, c2, out);
}

// Round 4
// 216.562 us; speedup vs baseline: 1.3868x; 1.3868x over previous
//
#include <hip/hip_runtime.h>
#include <cmath>

constexpr int BB = 4, CC = 64, HH = 256, WW = 256;
constexpr int WP = 258;   // padded width: cols -1..256 stored at col+1
constexpr int C2R = 257;  // c2 rows -1..255 stored at r+1

typedef short short8 __attribute__((ext_vector_type(8)));
typedef float f32x4 __attribute__((ext_vector_type(4)));
#define MFMA_BF16 __builtin_amdgcn_mfma_f32_16x16x32_bf16

union U16x8 { uint4 v; unsigned short h[8]; };

__device__ inline unsigned short f2bf(float f) {
  unsigned u = __builtin_bit_cast(unsigned, f);
  u += 0x7fffu + ((u >> 16) & 1u);
  return (unsigned short)(u >> 16);
}
__device__ inline float bf2f(unsigned short h) {
  unsigned u = ((unsigned)h) << 16;
  return __builtin_bit_cast(float, u);
}

// ---------------------------------------------------------------------------
// k_pack: block (y, b). NCHW fp32 -> col-padded NHWC bf16 (width 258, zero
// cols at 0 and 257), fused channel-max -> s. Transpose tile padded to 257
// so the strided read (c8*8+j)*257+px spreads across banks (was 8-way).
// ---------------------------------------------------------------------------
__global__ __launch_bounds__(256, 2) void k_pack(const float* __restrict__ x,
                                                 float* __restrict__ s,
                                                 unsigned short* __restrict__ xn) {
  __shared__ float tile[CC * 257];
  const int t = threadIdx.x, y = blockIdx.x, b = blockIdx.y;
  const float* base = x + (size_t)b * CC * HH * WW + y * WW + t;
  float m = -1e30f;
#pragma unroll 8
  for (int c = 0; c < CC; ++c) {
    float v = base[(size_t)c * HH * WW];
    tile[c * 257 + t] = v;
    m = fmaxf(m, v);
  }
  s[(b * HH + y) * WW + t] = 25.0f / fminf(fmaxf(m, 1.0f), 50.0f);
  uint4* xn4 = (uint4*)xn;
  if (t < 16) {  // zero col pads
    int col = (t >> 3) ? (WP - 1) : 0, c8 = t & 7;
    xn4[(((size_t)(b * HH + y) * WP + col) * CC + c8 * 8) >> 3] =
        make_uint4(0, 0, 0, 0);
  }
  __syncthreads();
#pragma unroll
  for (int g = 0; g < 8; ++g) {
    int px = g * 32 + (t >> 3), c8 = t & 7;
    U16x8 r;
#pragma unroll
    for (int j = 0; j < 8; ++j) r.h[j] = f2bf(tile[(c8 * 8 + j) * 257 + px]);
    xn4[(((size_t)(b * HH + y) * WP + px + 1) * CC + c8 * 8) >> 3] = r.v;
  }
}

// ---------------------------------------------------------------------------
// k_wpack: W [64][64][3][3] fp32 -> bf16 fragments Wp[tap][mt][kc][lane][8]
// value = W[o = mt*16 + (lane&15)][cin = kc*32 + (lane>>4)*8 + j][ky][kx]
// ---------------------------------------------------------------------------
__global__ __launch_bounds__(256) void k_wpack(const float* __restrict__ Wt,
                                               unsigned short* __restrict__ Wp) {
  int gid = blockIdx.x * 256 + threadIdx.x;  // 4608 total
  int lane = gid & 63, kc = (gid >> 6) & 1, mt = (gid >> 7) & 3, tap = gid >> 9;
  int o = mt * 16 + (lane & 15);
  int kb = kc * 32 + (lane >> 4) * 8;
  int ky = tap / 3, kx = tap % 3;
  U16x8 r;
#pragma unroll
  for (int j = 0; j < 8; ++j)
    r.h[j] = f2bf(Wt[o * 576 + (kb + j) * 9 + ky * 3 + kx]);
  ((uint4*)Wp)[gid] = r.v;
}

// ---------------------------------------------------------------------------
// k_warp: x2 row r = w0*xn[a0] + w1*xn[a1] (vertical bilinear), col-padded.
// ---------------------------------------------------------------------------
__global__ __launch_bounds__(256) void k_warp(const unsigned short* __restrict__ xn,
                                              const float* __restrict__ s,
                                              unsigned short* __restrict__ x2) {
  const int t = threadIdx.x, r = blockIdx.x, b = blockIdx.y;
  const uint4* xn4 = (const uint4*)xn;
  uint4* x24 = (uint4*)x2;
  if (t < 16) {
    int col = (t >> 3) ? (WP - 1) : 0, c8 = t & 7;
    x24[(((size_t)(b * HH + r) * WP + col) * CC + c8 * 8) >> 3] =
        make_uint4(0, 0, 0, 0);
  }
#pragma unroll
  for (int g = 0; g < 8; ++g) {
    int px = g * 32 + (t >> 3), c8 = t & 7;
    float sv = s[(b * HH + r) * WW + px];
    float ys = (float)r - sv;
    float fy = floorf(ys);
    float wfr = ys - fy;
    int i0 = (int)fy;
    float w0 = (i0 >= 0 && i0 < HH) ? 1.0f - wfr : 0.0f;
    float w1 = (i0 + 1 >= 0 && i0 + 1 < HH) ? wfr : 0.0f;
    int a0 = min(max(i0, 0), HH - 1), a1 = min(max(i0 + 1, 0), HH - 1);
    U16x8 u0, u1, rr;
    u0.v = xn4[(((size_t)(b * HH + a0) * WP + px + 1) * CC + c8 * 8) >> 3];
    u1.v = xn4[(((size_t)(b * HH + a1) * WP + px + 1) * CC + c8 * 8) >> 3];
#pragma unroll
    for (int k = 0; k < 8; ++k)
      rr.h[k] = f2bf(w0 * bf2f(u0.h[k]) + w1 * bf2f(u1.h[k]));
    x24[(((size_t)(b * HH + r) * WP + px + 1) * CC + c8 * 8) >> 3] = rr.v;
  }
}

// ---------------------------------------------------------------------------
// Shared conv-tile machinery: block computes 4 out rows x 64 cols x 64 och.
// LDS: 6 input rows x 66 padded cols x 8 chunks(8ch) uint4, XOR-swizzled.
// Wave w: och group ow=w&1 (32 och), row group rg=w>>1 (2 rows).
// Each X fragment read feeds up to 6 MFMAs (avg 3).
// ---------------------------------------------------------------------------
#define STAGE_TILE(src4, rowBase, colBase, bb)                                 \
  do {                                                                         \
    for (int i = 0; i < 13; ++i) {                                             \
      int idx = i * 256 + t;                                                   \
      if (idx < 3168) {                                                        \
        int rr_ = idx / 528, rem = idx % 528;                                  \
        int col_ = rem >> 3, ch_ = rem & 7;                                    \
        int xrow = (rowBase) + rr_;                                            \
        uint4 v = make_uint4(0, 0, 0, 0);                                      \
        if (xrow >= 0 && xrow < HH)                                            \
          v = src4[((size_t)((bb)*HH + xrow) * WP + (colBase) + col_) * 8 + ch_]; \
        lds[(rr_ * 66 + col_) * 8 + (ch_ ^ (col_ & 7))] = v;                   \
      }                                                                        \
    }                                                                          \
  } while (0)

// ---------------------------------------------------------------------------
// k_lower: c2 rows r0..r0+3, r0 = tr*4-1. D = W x X (och-major). bf16 NHWC out.
// ---------------------------------------------------------------------------
__global__ __launch_bounds__(256, 2) void k_lower(const unsigned short* __restrict__ x2,
                                                  const unsigned short* __restrict__ Wp,
                                                  unsigned short* __restrict__ c2) {
  __shared__ uint4 lds[3168];
  const int t = threadIdx.x;
  const int ctile = blockIdx.x & 3, tr = blockIdx.x >> 2;
  const int b = blockIdx.y;
  const int r0 = tr * 4 - 1;
  const int colBase = ctile * 64;

  const uint4* src4 = (const uint4*)x2;
  STAGE_TILE(src4, r0 - 1, colBase, b);

  const int lane = t & 63, w = t >> 6;
  const int ow = w & 1, rg = w >> 1, lr = rg * 2;
  const int quad = lane >> 4, l15 = lane & 15;

  short8 wf[9][2][2];
  const uint4* wp4 = (const uint4*)Wp;
#pragma unroll
  for (int tap = 0; tap < 9; ++tap)
#pragma unroll
    for (int ct = 0; ct < 2; ++ct)
#pragma unroll
      for (int kc = 0; kc < 2; ++kc)
        wf[tap][ct][kc] = __builtin_bit_cast(
            short8, wp4[((tap * 4 + (ow * 2 + ct)) * 2 + kc) * 64 + lane]);
  __syncthreads();

#pragma unroll 1
  for (int pt = 0; pt < 4; ++pt) {
    f32x4 acc[2][2] = {{{0.f, 0.f, 0.f, 0.f}, {0.f, 0.f, 0.f, 0.f}},
                       {{0.f, 0.f, 0.f, 0.f}, {0.f, 0.f, 0.f, 0.f}}};
#pragma unroll
    for (int ir = 0; ir < 4; ++ir) {
      int ldr = lr + ir;
#pragma unroll
      for (int kx = 0; kx < 3; ++kx) {
        int col = pt * 16 + l15 + kx;
        int cb = (ldr * 66 + col) * 8, sw = col & 7;
#pragma unroll
        for (int kc = 0; kc < 2; ++kc) {
          short8 xf = __builtin_bit_cast(short8, lds[cb + ((kc * 4 + quad) ^ sw)]);
          if (ir <= 2) {  // contributes to row rr=0 with ky=ir
#pragma unroll
            for (int ct = 0; ct < 2; ++ct)
              acc[0][ct] = MFMA_BF16(wf[ir * 3 + kx][ct][kc], xf, acc[0][ct], 0, 0, 0);
          }
          if (ir >= 1) {  // contributes to row rr=1 with ky=ir-1
#pragma unroll
            for (int ct = 0; ct < 2; ++ct)
              acc[1][ct] = MFMA_BF16(wf[(ir - 1) * 3 + kx][ct][kc], xf, acc[1][ct], 0, 0, 0);
          }
        }
      }
    }
#pragma unroll
    for (int rr = 0; rr < 2; ++rr) {
      int r = r0 + lr + rr;
      if (r > 255) continue;
      int px = colBase + pt * 16 + l15;
#pragma unroll
      for (int ct = 0; ct < 2; ++ct) {
        f32x4 A = acc[rr][ct];
        int ch = (ow * 2 + ct) * 16 + quad * 4;
        unsigned short h0 = f2bf(A[0]), h1 = f2bf(A[1]), h2 = f2bf(A[2]), h3 = f2bf(A[3]);
        uint2 val = make_uint2((unsigned)h0 | ((unsigned)h1 << 16),
                               (unsigned)h2 | ((unsigned)h3 << 16));
        *(uint2*)(c2 + (((size_t)(b * C2R + (r + 1)) * WW + px) * CC + ch)) = val;
      }
    }
  }
}

// ---------------------------------------------------------------------------
// k_final: out rows y0..y0+3. D = X x W (px-major) + c2 resample + min.
// ---------------------------------------------------------------------------
__global__ __launch_bounds__(256, 2) void k_final(const unsigned short* __restrict__ xn,
                                                  const unsigned short* __restrict__ Wp,
                                                  const float* __restrict__ s,
                                                  const unsigned short* __restrict__ c2,
                                                  float* __restrict__ out) {
  __shared__ uint4 lds[3168];
  const int t = threadIdx.x;
  const int ctile = blockIdx.x & 3, tr = blockIdx.x >> 2;
  const int b = blockIdx.y;
  const int y0 = tr * 4;
  const int colBase = ctile * 64;

  const uint4* src4 = (const uint4*)xn;
  STAGE_TILE(src4, y0 - 1, colBase, b);

  const int lane = t & 63, w = t >> 6;
  const int ow = w & 1, rg = w >> 1, lr = rg * 2;
  const int quad = lane >> 4, l15 = lane & 15;

  short8 wf[9][2][2];
  const uint4* wp4 = (const uint4*)Wp;
#pragma unroll
  for (int tap = 0; tap < 9; ++tap)
#pragma unroll
    for (int ct = 0; ct < 2; ++ct)
#pragma unroll
      for (int kc = 0; kc < 2; ++kc)
        wf[tap][ct][kc] = __builtin_bit_cast(
            short8, wp4[((tap * 4 + (ow * 2 + ct)) * 2 + kc) * 64 + lane]);
  __syncthreads();

#pragma unroll 1
  for (int pt = 0; pt < 4; ++pt) {
    f32x4 acc[2][2] = {{{0.f, 0.f, 0.f, 0.f}, {0.f, 0.f, 0.f, 0.f}},
                       {{0.f, 0.f, 0.f, 0.f}, {0.f, 0.f, 0.f, 0.f}}};
#pragma unroll
    for (int ir = 0; ir < 4; ++ir) {
      int ldr = lr + ir;
#pragma unroll
      for (int kx = 0; kx < 3; ++kx) {
        int col = pt * 16 + l15 + kx;
        int cb = (ldr * 66 + col) * 8, sw = col & 7;
#pragma unroll
        for (int kc = 0; kc < 2; ++kc) {
          short8 xf = __builtin_bit_cast(short8, lds[cb + ((kc * 4 + quad) ^ sw)]);
          if (ir <= 2) {
#pragma unroll
            for (int ct = 0; ct < 2; ++ct)
              acc[0][ct] = MFMA_BF16(xf, wf[ir * 3 + kx][ct][kc], acc[0][ct], 0, 0, 0);
          }
          if (ir >= 1) {
#pragma unroll
            for (int ct = 0; ct < 2; ++ct)
              acc[1][ct] = MFMA_BF16(xf, wf[(ir - 1) * 3 + kx][ct][kc], acc[1][ct], 0, 0, 0);
          }
        }
      }
    }
#pragma unroll
    for (int rr = 0; rr < 2; ++rr) {
      int y = y0 + lr + rr;
      int px0 = colBase + pt * 16 + quad * 4;
      f32x4 sv4 = *(const f32x4*)(s + (b * HH + y) * WW + px0);
      float lw0[4], lw1[4];
      int a0i[4], a1i[4];
#pragma unroll
      for (int j = 0; j < 4; ++j) {
        float ys = (float)y - sv4[j];
        float fy = floorf(ys);
        float wfr = ys - fy;
        int i0 = (int)fy;
        lw0[j] = (i0 + 1 >= 0 && i0 + 1 <= HH) ? 1.0f - wfr : 0.0f;
        lw1[j] = (i0 + 2 >= 0 && i0 + 2 <= HH) ? wfr : 0.0f;
        a0i[j] = min(max(i0 + 1, 0), HH);
        a1i[j] = min(max(i0 + 2, 0), HH);
      }
#pragma unroll
      for (int ct = 0; ct < 2; ++ct) {
        f32x4 A = acc[rr][ct];
        int ch = (ow * 2 + ct) * 16 + l15;
        f32x4 res;
#pragma unroll
        for (int j = 0; j < 4; ++j) {
          int px = px0 + j;
          float v0 = bf2f(c2[((size_t)(b * C2R + a0i[j]) * WW + px) * CC + ch]);
          float v1 = bf2f(c2[((size_t)(b * C2R + a1i[j]) * WW + px) * CC + ch]);
          res[j] = fminf(A[j], lw0[j] * v0 + lw1[j] * v1);
        }
        *(f32x4*)(out + ((size_t)(b * CC + ch) * HH + y) * WW + px0) = res;
      }
    }
  }
}

// ---------------------------------------------------------------------------
extern "C" void kernel_launch(void* const* d_in, const int* in_sizes, int n_in,
                              void* d_out, int out_size, void* d_ws, size_t ws_size,
                              hipStream_t stream) {
  const float* x = (const float*)d_in[0];
  const float* Wt = (const float*)d_in[1];
  float* out = (float*)d_out;

  char* ws = (char*)d_ws;
  float* s = (float*)ws;                                   //   1,048,576 B
  unsigned short* Wp = (unsigned short*)(ws + 1048576);    //      73,728 B
  unsigned short* xn = (unsigned short*)(ws + 1122304);    //  33,816,576 B
  unsigned short* x2 = (unsigned short*)(ws + 34938880);   //  33,816,576 B
  unsigned short* c2 = (unsigned short*)(ws + 68755456);   //  33,685,504 B
                                                           // total 102.4 MB
  k_pack<<<dim3(HH, BB), 256, 0, stream>>>(x, s, xn);
  k_wpack<<<dim3(18), 256, 0, stream>>>(Wt, Wp);
  k_warp<<<dim3(HH, BB), 256, 0, stream>>>(xn, s, x2);
  k_lower<<<dim3(4 * 65, BB), 256, 0, stream>>>(x2, Wp, c2);
  k_final<<<dim3(4 * 64, BB), 256, 0, stream>>>(xn, Wp, s, c2, out);
}

// Round 5
// 197.207 us; speedup vs baseline: 1.5229x; 1.0981x over previous
//
#include <hip/hip_runtime.h>
#include <cmath>

constexpr int BB = 4, CC = 64, HH = 256, WW = 256;
constexpr int WP = 258;   // padded width: cols -1..256 stored at col+1
constexpr int C2R = 257;  // c2 rows -1..255 stored at r+1

typedef short short8 __attribute__((ext_vector_type(8)));
typedef float f32x4 __attribute__((ext_vector_type(4)));
#define MFMA_BF16 __builtin_amdgcn_mfma_f32_16x16x32_bf16

union U16x8 { uint4 v; unsigned short h[8]; };
union U16x4 { uint2 v; unsigned short h[4]; };

__device__ inline unsigned short f2bf(float f) {
  unsigned u = __builtin_bit_cast(unsigned, f);
  u += 0x7fffu + ((u >> 16) & 1u);
  return (unsigned short)(u >> 16);
}
__device__ inline unsigned short f2bf_trunc(float f) {
  return (unsigned short)(__builtin_bit_cast(unsigned, f) >> 16);
}
__device__ inline float bf2f(unsigned short h) {
  unsigned u = ((unsigned)h) << 16;
  return __builtin_bit_cast(float, u);
}

// ---------------------------------------------------------------------------
// k_pack: block (y, b). NCHW fp32 -> col-padded NHWC bf16 (zero cols 0, 257),
// fused channel-max -> s. Transpose tile padded to 257 (bank-conflict-free).
// ---------------------------------------------------------------------------
__global__ __launch_bounds__(256, 2) void k_pack(const float* __restrict__ x,
                                                 float* __restrict__ s,
                                                 unsigned short* __restrict__ xn) {
  __shared__ float tile[CC * 257];
  const int t = threadIdx.x, y = blockIdx.x, b = blockIdx.y;
  const float* base = x + (size_t)b * CC * HH * WW + y * WW + t;
  float m = -1e30f;
#pragma unroll 8
  for (int c = 0; c < CC; ++c) {
    float v = base[(size_t)c * HH * WW];
    tile[c * 257 + t] = v;
    m = fmaxf(m, v);
  }
  s[(b * HH + y) * WW + t] = 25.0f / fminf(fmaxf(m, 1.0f), 50.0f);
  uint4* xn4 = (uint4*)xn;
  if (t < 16) {  // zero col pads
    int col = (t >> 3) ? (WP - 1) : 0, c8 = t & 7;
    xn4[(((size_t)(b * HH + y) * WP + col) * CC + c8 * 8) >> 3] =
        make_uint4(0, 0, 0, 0);
  }
  __syncthreads();
#pragma unroll
  for (int g = 0; g < 8; ++g) {
    int px = g * 32 + (t >> 3), c8 = t & 7;
    U16x8 r;
#pragma unroll
    for (int j = 0; j < 8; ++j) r.h[j] = f2bf(tile[(c8 * 8 + j) * 257 + px]);
    xn4[(((size_t)(b * HH + y) * WP + px + 1) * CC + c8 * 8) >> 3] = r.v;
  }
}

// ---------------------------------------------------------------------------
// k_wpack: W [64][64][3][3] fp32 -> bf16 fragments Wp[tap][mt][kc][lane][8]
// value = W[o = mt*16 + (lane&15)][cin = kc*32 + (lane>>4)*8 + j][ky][kx]
// ---------------------------------------------------------------------------
__global__ __launch_bounds__(256) void k_wpack(const float* __restrict__ Wt,
                                               unsigned short* __restrict__ Wp) {
  int gid = blockIdx.x * 256 + threadIdx.x;  // 4608 total
  int lane = gid & 63, kc = (gid >> 6) & 1, mt = (gid >> 7) & 3, tap = gid >> 9;
  int o = mt * 16 + (lane & 15);
  int kb = kc * 32 + (lane >> 4) * 8;
  int ky = tap / 3, kx = tap % 3;
  U16x8 r;
#pragma unroll
  for (int j = 0; j < 8; ++j)
    r.h[j] = f2bf(Wt[o * 576 + (kb + j) * 9 + ky * 3 + kx]);
  ((uint4*)Wp)[gid] = r.v;
}

// ---------------------------------------------------------------------------
// Conv tile: block = 4 out rows x 64 cols x 64 och.
// LDS: 6 input rows x 66 padded cols x 8 chunks(8ch) uint4, XOR-swizzled.
// Waves: ow = w&1 (32-och group), rg = w>>1 (2-row group).
// ---------------------------------------------------------------------------
#define STAGE_TILE(src4, rowBase, colBase, bb)                                 \
  do {                                                                         \
    for (int i = 0; i < 13; ++i) {                                             \
      int idx = i * 256 + t;                                                   \
      if (idx < 3168) {                                                        \
        int rr_ = idx / 528, rem = idx % 528;                                  \
        int col_ = rem >> 3, ch_ = rem & 7;                                    \
        int xrow = (rowBase) + rr_;                                            \
        uint4 v = make_uint4(0, 0, 0, 0);                                      \
        if (xrow >= 0 && xrow < HH)                                            \
          v = src4[((size_t)((bb)*HH + xrow) * WP + (colBase) + col_) * 8 + ch_]; \
        lds[(rr_ * 66 + col_) * 8 + (ch_ ^ (col_ & 7))] = v;                   \
      }                                                                        \
    }                                                                          \
  } while (0)

// ---------------------------------------------------------------------------
// k_lower: c2 rows r0..r0+3, r0 = tr*4-1. Staging does the vertical bilinear
// warp on the fly (x2 never materialized). D = W x X (och-major), bf16 NHWC.
// ---------------------------------------------------------------------------
__global__ __launch_bounds__(256, 2) void k_lower(const unsigned short* __restrict__ xn,
                                                  const unsigned short* __restrict__ Wp,
                                                  const float* __restrict__ s,
                                                  unsigned short* __restrict__ c2) {
  __shared__ uint4 lds[3168];
  const int t = threadIdx.x;
  const int ctile = blockIdx.x & 3, tr = blockIdx.x >> 2;
  const int b = blockIdx.y;
  const int r0 = tr * 4 - 1;
  const int colBase = ctile * 64;

  const uint4* xn4 = (const uint4*)xn;
  // fused warp + stage: staged row rr_ is x2 row (r0-2+rr_+1) = r0-1+rr_
  for (int i = 0; i < 13; ++i) {
    int idx = i * 256 + t;
    if (idx < 3168) {
      int rr_ = idx / 528, rem = idx % 528;
      int col_ = rem >> 3, ch_ = rem & 7;
      int xrow = r0 - 1 + rr_;  // x2 row index, [-2..259]
      uint4 v = make_uint4(0, 0, 0, 0);
      if (xrow >= 0 && xrow < HH) {
        int px = colBase + col_ - 1;               // -1..256 (pad cols give 0)
        int pxc = min(max(px, 0), WW - 1);
        float sv = s[(b * HH + xrow) * WW + pxc];
        float ys = (float)xrow - sv;
        float fy = floorf(ys);
        float wfr = ys - fy;
        int i0 = (int)fy;                          // <= xrow-1 <= 254
        float w0 = (i0 >= 0) ? 1.0f - wfr : 0.0f;
        float w1 = (i0 + 1 >= 0) ? wfr : 0.0f;
        int a0 = max(i0, 0), a1 = max(i0 + 1, 0);
        U16x8 u0, u1, rr;
        u0.v = xn4[((size_t)(b * HH + a0) * WP + colBase + col_) * 8 + ch_];
        u1.v = xn4[((size_t)(b * HH + a1) * WP + colBase + col_) * 8 + ch_];
#pragma unroll
        for (int k = 0; k < 8; ++k)
          rr.h[k] = f2bf_trunc(w0 * bf2f(u0.h[k]) + w1 * bf2f(u1.h[k]));
        v = rr.v;
      }
      lds[(rr_ * 66 + col_) * 8 + (ch_ ^ (col_ & 7))] = v;
    }
  }

  const int lane = t & 63, w = t >> 6;
  const int ow = w & 1, rg = w >> 1, lr = rg * 2;
  const int quad = lane >> 4, l15 = lane & 15;

  short8 wf[9][2][2];
  const uint4* wp4 = (const uint4*)Wp;
#pragma unroll
  for (int tap = 0; tap < 9; ++tap)
#pragma unroll
    for (int ct = 0; ct < 2; ++ct)
#pragma unroll
      for (int kc = 0; kc < 2; ++kc)
        wf[tap][ct][kc] = __builtin_bit_cast(
            short8, wp4[((tap * 4 + (ow * 2 + ct)) * 2 + kc) * 64 + lane]);
  __syncthreads();

#pragma unroll 1
  for (int pt = 0; pt < 4; ++pt) {
    f32x4 acc[2][2] = {{{0.f, 0.f, 0.f, 0.f}, {0.f, 0.f, 0.f, 0.f}},
                       {{0.f, 0.f, 0.f, 0.f}, {0.f, 0.f, 0.f, 0.f}}};
#pragma unroll
    for (int ir = 0; ir < 4; ++ir) {
      int ldr = lr + ir;
#pragma unroll
      for (int kx = 0; kx < 3; ++kx) {
        int col = pt * 16 + l15 + kx;
        int cb = (ldr * 66 + col) * 8, sw = col & 7;
#pragma unroll
        for (int kc = 0; kc < 2; ++kc) {
          short8 xf = __builtin_bit_cast(short8, lds[cb + ((kc * 4 + quad) ^ sw)]);
          if (ir <= 2) {
#pragma unroll
            for (int ct = 0; ct < 2; ++ct)
              acc[0][ct] = MFMA_BF16(wf[ir * 3 + kx][ct][kc], xf, acc[0][ct], 0, 0, 0);
          }
          if (ir >= 1) {
#pragma unroll
            for (int ct = 0; ct < 2; ++ct)
              acc[1][ct] = MFMA_BF16(wf[(ir - 1) * 3 + kx][ct][kc], xf, acc[1][ct], 0, 0, 0);
          }
        }
      }
    }
#pragma unroll
    for (int rr = 0; rr < 2; ++rr) {
      int r = r0 + lr + rr;
      if (r > 255) continue;
      int px = colBase + pt * 16 + l15;
#pragma unroll
      for (int ct = 0; ct < 2; ++ct) {
        f32x4 A = acc[rr][ct];
        int ch = (ow * 2 + ct) * 16 + quad * 4;
        unsigned short h0 = f2bf(A[0]), h1 = f2bf(A[1]), h2 = f2bf(A[2]), h3 = f2bf(A[3]);
        uint2 val = make_uint2((unsigned)h0 | ((unsigned)h1 << 16),
                               (unsigned)h2 | ((unsigned)h3 << 16));
        *(uint2*)(c2 + (((size_t)(b * C2R + (r + 1)) * WW + px) * CC + ch)) = val;
      }
    }
  }
}

// ---------------------------------------------------------------------------
// k_final: out rows y0..y0+3. D = W x X (och-major: lane = 4 och at one px)
// so the c2 resample is uint2-vectorized. Store dword per och (64B segments).
// ---------------------------------------------------------------------------
__global__ __launch_bounds__(256, 2) void k_final(const unsigned short* __restrict__ xn,
                                                  const unsigned short* __restrict__ Wp,
                                                  const float* __restrict__ s,
                                                  const unsigned short* __restrict__ c2,
                                                  float* __restrict__ out) {
  __shared__ uint4 lds[3168];
  const int t = threadIdx.x;
  const int ctile = blockIdx.x & 3, tr = blockIdx.x >> 2;
  const int b = blockIdx.y;
  const int y0 = tr * 4;
  const int colBase = ctile * 64;

  const uint4* src4 = (const uint4*)xn;
  STAGE_TILE(src4, y0 - 1, colBase, b);

  const int lane = t & 63, w = t >> 6;
  const int ow = w & 1, rg = w >> 1, lr = rg * 2;
  const int quad = lane >> 4, l15 = lane & 15;

  short8 wf[9][2][2];
  const uint4* wp4 = (const uint4*)Wp;
#pragma unroll
  for (int tap = 0; tap < 9; ++tap)
#pragma unroll
    for (int ct = 0; ct < 2; ++ct)
#pragma unroll
      for (int kc = 0; kc < 2; ++kc)
        wf[tap][ct][kc] = __builtin_bit_cast(
            short8, wp4[((tap * 4 + (ow * 2 + ct)) * 2 + kc) * 64 + lane]);
  __syncthreads();

#pragma unroll 1
  for (int pt = 0; pt < 4; ++pt) {
    f32x4 acc[2][2] = {{{0.f, 0.f, 0.f, 0.f}, {0.f, 0.f, 0.f, 0.f}},
                       {{0.f, 0.f, 0.f, 0.f}, {0.f, 0.f, 0.f, 0.f}}};
#pragma unroll
    for (int ir = 0; ir < 4; ++ir) {
      int ldr = lr + ir;
#pragma unroll
      for (int kx = 0; kx < 3; ++kx) {
        int col = pt * 16 + l15 + kx;
        int cb = (ldr * 66 + col) * 8, sw = col & 7;
#pragma unroll
        for (int kc = 0; kc < 2; ++kc) {
          short8 xf = __builtin_bit_cast(short8, lds[cb + ((kc * 4 + quad) ^ sw)]);
          if (ir <= 2) {
#pragma unroll
            for (int ct = 0; ct < 2; ++ct)
              acc[0][ct] = MFMA_BF16(wf[ir * 3 + kx][ct][kc], xf, acc[0][ct], 0, 0, 0);
          }
          if (ir >= 1) {
#pragma unroll
            for (int ct = 0; ct < 2; ++ct)
              acc[1][ct] = MFMA_BF16(wf[(ir - 1) * 3 + kx][ct][kc], xf, acc[1][ct], 0, 0, 0);
          }
        }
      }
    }
    int px = colBase + pt * 16 + l15;
#pragma unroll
    for (int rr = 0; rr < 2; ++rr) {
      int y = y0 + lr + rr;
      float sv = s[(b * HH + y) * WW + px];
      float ys = (float)y - sv;
      float fy = floorf(ys);
      float wfr = ys - fy;
      int i0 = (int)fy;
      float lw0 = (i0 + 1 >= 0 && i0 + 1 <= HH) ? 1.0f - wfr : 0.0f;
      float lw1 = (i0 + 2 >= 0 && i0 + 2 <= HH) ? wfr : 0.0f;
      int a0 = min(max(i0 + 1, 0), HH);
      int a1 = min(max(i0 + 2, 0), HH);
#pragma unroll
      for (int ct = 0; ct < 2; ++ct) {
        f32x4 A = acc[rr][ct];
        int ch = (ow * 2 + ct) * 16 + quad * 4;
        U16x4 v0, v1;
        v0.v = *(const uint2*)(c2 + ((size_t)(b * C2R + a0) * WW + px) * CC + ch);
        v1.v = *(const uint2*)(c2 + ((size_t)(b * C2R + a1) * WW + px) * CC + ch);
#pragma unroll
        for (int reg = 0; reg < 4; ++reg) {
          float lower = lw0 * bf2f(v0.h[reg]) + lw1 * bf2f(v1.h[reg]);
          out[((size_t)(b * CC + ch + reg) * HH + y) * WW + px] =
              fminf(A[reg], lower);
        }
      }
    }
  }
}

// ---------------------------------------------------------------------------
extern "C" void kernel_launch(void* const* d_in, const int* in_sizes, int n_in,
                              void* d_out, int out_size, void* d_ws, size_t ws_size,
                              hipStream_t stream) {
  const float* x = (const float*)d_in[0];
  const float* Wt = (const float*)d_in[1];
  float* out = (float*)d_out;

  char* ws = (char*)d_ws;
  float* s = (float*)ws;                                   //   1,048,576 B
  unsigned short* Wp = (unsigned short*)(ws + 1048576);    //      73,728 B
  unsigned short* xn = (unsigned short*)(ws + 1122304);    //  33,816,576 B
  unsigned short* c2 = (unsigned short*)(ws + 34938880);   //  33,685,504 B
                                                           // total 68.6 MB
  k_pack<<<dim3(HH, BB), 256, 0, stream>>>(x, s, xn);
  k_wpack<<<dim3(18), 256, 0, stream>>>(Wt, Wp);
  k_lower<<<dim3(4 * 65, BB), 256, 0, stream>>>(xn, Wp, s, c2);
  k_final<<<dim3(4 * 64, BB), 256, 0, stream>>>(xn, Wp, s, c2, out);
}

// Round 7
// 195.418 us; speedup vs baseline: 1.5368x; 1.0092x over previous
//
#include <hip/hip_runtime.h>
#include <cmath>

constexpr int BB = 4, CC = 64, HH = 256, WW = 256;
constexpr int WP = 258;   // padded width: cols -1..256 stored at col+1
constexpr int C2R = 257;  // c2 rows -1..255 stored at r+1

typedef short short8 __attribute__((ext_vector_type(8)));
typedef float f32x4 __attribute__((ext_vector_type(4)));
#define MFMA_BF16 __builtin_amdgcn_mfma_f32_16x16x32_bf16

union U16x8 { uint4 v; unsigned short h[8]; };
union U16x4 { uint2 v; unsigned short h[4]; };

__device__ inline unsigned short f2bf(float f) {
  unsigned u = __builtin_bit_cast(unsigned, f);
  u += 0x7fffu + ((u >> 16) & 1u);
  return (unsigned short)(u >> 16);
}
__device__ inline unsigned short f2bf_trunc(float f) {
  return (unsigned short)(__builtin_bit_cast(unsigned, f) >> 16);
}
__device__ inline float bf2f(unsigned short h) {
  unsigned u = ((unsigned)h) << 16;
  return __builtin_bit_cast(float, u);
}

// ---------------------------------------------------------------------------
// k_pack: block = half-row (128 px) of one (y,b). NCHW fp32 -> col-padded
// NHWC bf16 + fused channel-max -> s. 33 KB LDS -> 4 blocks/CU.
// ---------------------------------------------------------------------------
__global__ __launch_bounds__(256, 4) void k_pack(const float* __restrict__ x,
                                                 float* __restrict__ s,
                                                 unsigned short* __restrict__ xn) {
  __shared__ float tile[CC * 129];
  __shared__ float pmax[2][128];
  const int t = threadIdx.x;
  const int half = blockIdx.x & 1, y = blockIdx.x >> 1, b = blockIdx.y;
  const int px0 = half * 128;
  const int pxl = t & 127, chb = (t >> 7) * 32;

  const float* base = x + (size_t)b * CC * HH * WW + (size_t)y * WW + px0 + pxl;
  float m = -1e30f;
#pragma unroll 8
  for (int i = 0; i < 32; ++i) {
    float v = base[(size_t)(chb + i) * HH * WW];
    tile[(chb + i) * 129 + pxl] = v;
    m = fmaxf(m, v);
  }
  pmax[t >> 7][pxl] = m;

  uint4* xn4 = (uint4*)xn;
  if (t < 8) {  // zero col pad (col 0 from half 0, col 257 from half 1)
    int col = half ? (WP - 1) : 0;
    xn4[(((size_t)(b * HH + y) * WP + col) * CC + t * 8) >> 3] =
        make_uint4(0, 0, 0, 0);
  }
  __syncthreads();

  if (t < 128) {
    float mm = fmaxf(pmax[0][t], pmax[1][t]);
    s[(b * HH + y) * WW + px0 + t] = 25.0f / fminf(fmaxf(mm, 1.0f), 50.0f);
  }
#pragma unroll
  for (int g = 0; g < 4; ++g) {
    int px = g * 32 + (t >> 3), c8 = t & 7;
    U16x8 r;
#pragma unroll
    for (int j = 0; j < 8; ++j) r.h[j] = f2bf(tile[(c8 * 8 + j) * 129 + px]);
    xn4[(((size_t)(b * HH + y) * WP + px0 + px + 1) * CC + c8 * 8) >> 3] = r.v;
  }
}

// ---------------------------------------------------------------------------
// k_wpack: W [64][64][3][3] fp32 -> bf16 fragments Wp[tap][mt][kc][lane][8]
// value = W[o = mt*16 + (lane&15)][cin = kc*32 + (lane>>4)*8 + j][ky][kx]
// ---------------------------------------------------------------------------
__global__ __launch_bounds__(256) void k_wpack(const float* __restrict__ Wt,
                                               unsigned short* __restrict__ Wp) {
  int gid = blockIdx.x * 256 + threadIdx.x;  // 4608 total
  int lane = gid & 63, kc = (gid >> 6) & 1, mt = (gid >> 7) & 3, tap = gid >> 9;
  int o = mt * 16 + (lane & 15);
  int kb = kc * 32 + (lane >> 4) * 8;
  int ky = tap / 3, kx = tap % 3;
  U16x8 r;
#pragma unroll
  for (int j = 0; j < 8; ++j)
    r.h[j] = f2bf(Wt[o * 576 + (kb + j) * 9 + ky * 3 + kx]);
  ((uint4*)Wp)[gid] = r.v;
}

// ---------------------------------------------------------------------------
// Conv tile: block = 4 out rows x 64 cols x 64 och.
// LDS: 6 input rows x 66 padded cols x 8 chunks(8ch) uint4, XOR-swizzled.
// Waves: ow = w&1 (32-och group), rg = w>>1 (2-row group).
// MFMA loop: pt-pair outer, kc outer inside -> only 18 weight frags live.
// ---------------------------------------------------------------------------
__global__ __launch_bounds__(256, 3) void k_lower(const unsigned short* __restrict__ xn,
                                                  const unsigned short* __restrict__ Wp,
                                                  const float* __restrict__ s,
                                                  unsigned short* __restrict__ c2) {
  __shared__ uint4 lds[3168];
  const int t = threadIdx.x;
  const int ctile = blockIdx.x & 3, tr = blockIdx.x >> 2;
  const int b = blockIdx.y;
  const int r0 = tr * 4 - 1;
  const int colBase = ctile * 64;

  const uint4* xn4 = (const uint4*)xn;
  // ---- staging phase 1: params + independent s loads ----
  float w0a[13], w1a[13];
  int o0a[13], o1a[13], la[13];
  bool act[13], va[13];
#pragma unroll
  for (int i = 0; i < 13; ++i) {
    int idx = i * 256 + t;
    act[i] = (idx < 3168);
    int rr_ = idx / 528, rem = idx % 528;
    int col_ = rem >> 3, ch_ = rem & 7;
    int xrow = r0 - 1 + rr_;  // x2 row index
    va[i] = act[i] && (xrow >= 0) && (xrow < HH);
    la[i] = (rr_ * 66 + col_) * 8 + (ch_ ^ (col_ & 7));
    float sv = 0.0f;
    int pxc = min(max(colBase + col_ - 1, 0), WW - 1);
    if (va[i]) sv = s[(b * HH + xrow) * WW + pxc];
    float ys = (float)xrow - sv;
    float fy = floorf(ys);
    float wfr = ys - fy;
    int i0 = (int)fy;
    w0a[i] = (i0 >= 0) ? 1.0f - wfr : 0.0f;
    w1a[i] = (i0 + 1 >= 0) ? wfr : 0.0f;
    int a0 = max(i0, 0), a1 = max(i0 + 1, 0);
    o0a[i] = ((b * HH + a0) * WP + colBase + col_) * 8 + ch_;
    o1a[i] = ((b * HH + a1) * WP + colBase + col_) * 8 + ch_;
  }
  // ---- staging phase 2: gathers + blend + LDS write ----
#pragma unroll
  for (int i = 0; i < 13; ++i) {
    if (act[i]) {
      uint4 v = make_uint4(0, 0, 0, 0);
      if (va[i]) {
        U16x8 u0, u1, rr;
        u0.v = xn4[o0a[i]];
        u1.v = xn4[o1a[i]];
#pragma unroll
        for (int k = 0; k < 8; ++k)
          rr.h[k] = f2bf_trunc(w0a[i] * bf2f(u0.h[k]) + w1a[i] * bf2f(u1.h[k]));
        v = rr.v;
      }
      lds[la[i]] = v;
    }
  }

  const int lane = t & 63, w = t >> 6;
  const int ow = w & 1, rg = w >> 1, lr = rg * 2;
  const int quad = lane >> 4, l15 = lane & 15;
  const uint4* wp4 = (const uint4*)Wp;
  __syncthreads();

#pragma unroll 1
  for (int pp = 0; pp < 2; ++pp) {
    f32x4 acc[2][2][2];  // [ptInPair][rr][ct]
#pragma unroll
    for (int pi = 0; pi < 2; ++pi)
#pragma unroll
      for (int rr = 0; rr < 2; ++rr)
#pragma unroll
        for (int ct = 0; ct < 2; ++ct) acc[pi][rr][ct] = {0.f, 0.f, 0.f, 0.f};

#pragma unroll 1
    for (int kc = 0; kc < 2; ++kc) {
      short8 wf[9][2];
#pragma unroll
      for (int tap = 0; tap < 9; ++tap)
#pragma unroll
        for (int ct = 0; ct < 2; ++ct)
          wf[tap][ct] = __builtin_bit_cast(
              short8, wp4[((tap * 4 + (ow * 2 + ct)) * 2 + kc) * 64 + lane]);
#pragma unroll
      for (int pi = 0; pi < 2; ++pi) {
        int pt = pp * 2 + pi;
#pragma unroll
        for (int ir = 0; ir < 4; ++ir) {
          int ldr = lr + ir;
#pragma unroll
          for (int kx = 0; kx < 3; ++kx) {
            int col = pt * 16 + l15 + kx;
            short8 xf = __builtin_bit_cast(
                short8, lds[(ldr * 66 + col) * 8 + ((kc * 4 + quad) ^ (col & 7))]);
            if (ir <= 2) {
#pragma unroll
              for (int ct = 0; ct < 2; ++ct)
                acc[pi][0][ct] = MFMA_BF16(wf[ir * 3 + kx][ct], xf, acc[pi][0][ct], 0, 0, 0);
            }
            if (ir >= 1) {
#pragma unroll
              for (int ct = 0; ct < 2; ++ct)
                acc[pi][1][ct] = MFMA_BF16(wf[(ir - 1) * 3 + kx][ct], xf, acc[pi][1][ct], 0, 0, 0);
            }
          }
        }
      }
    }
    // epilogue for pts 2pp, 2pp+1
#pragma unroll
    for (int pi = 0; pi < 2; ++pi) {
      int px = colBase + (pp * 2 + pi) * 16 + l15;
#pragma unroll
      for (int rr = 0; rr < 2; ++rr) {
        int r = r0 + lr + rr;
        if (r > 255) continue;
#pragma unroll
        for (int ct = 0; ct < 2; ++ct) {
          f32x4 A = acc[pi][rr][ct];
          int ch = (ow * 2 + ct) * 16 + quad * 4;
          unsigned short h0 = f2bf(A[0]), h1 = f2bf(A[1]), h2 = f2bf(A[2]), h3 = f2bf(A[3]);
          uint2 val = make_uint2((unsigned)h0 | ((unsigned)h1 << 16),
                                 (unsigned)h2 | ((unsigned)h3 << 16));
          *(uint2*)(c2 + (((size_t)(b * C2R + (r + 1)) * WW + px) * CC + ch)) = val;
        }
      }
    }
  }
}

// ---------------------------------------------------------------------------
// k_final: out rows y0..y0+3, och-major MFMA (D = W x X) so the c2 resample
// is uint2-vectorized. Same pt-pair/kc loop structure as k_lower.
// Staged input rows are y0-1 .. y0+4  (xrow = y0 - 1 + rr_  — round-6 bug
// was y0-2 here).
// ---------------------------------------------------------------------------
__global__ __launch_bounds__(256, 3) void k_final(const unsigned short* __restrict__ xn,
                                                  const unsigned short* __restrict__ Wp,
                                                  const float* __restrict__ s,
                                                  const unsigned short* __restrict__ c2,
                                                  float* __restrict__ out) {
  __shared__ uint4 lds[3168];
  const int t = threadIdx.x;
  const int ctile = blockIdx.x & 3, tr = blockIdx.x >> 2;
  const int b = blockIdx.y;
  const int y0 = tr * 4;
  const int colBase = ctile * 64;

  const uint4* src4 = (const uint4*)xn;
#pragma unroll
  for (int i = 0; i < 13; ++i) {
    int idx = i * 256 + t;
    if (idx < 3168) {
      int rr_ = idx / 528, rem = idx % 528;
      int col_ = rem >> 3, ch_ = rem & 7;
      int xrow = y0 - 1 + rr_;  // rows y0-1 .. y0+4
      uint4 v = make_uint4(0, 0, 0, 0);
      if (xrow >= 0 && xrow < HH)
        v = src4[((size_t)(b * HH + xrow) * WP + colBase + col_) * 8 + ch_];
      lds[(rr_ * 66 + col_) * 8 + (ch_ ^ (col_ & 7))] = v;
    }
  }

  const int lane = t & 63, w = t >> 6;
  const int ow = w & 1, rg = w >> 1, lr = rg * 2;
  const int quad = lane >> 4, l15 = lane & 15;
  const uint4* wp4 = (const uint4*)Wp;
  __syncthreads();

#pragma unroll 1
  for (int pp = 0; pp < 2; ++pp) {
    f32x4 acc[2][2][2];
#pragma unroll
    for (int pi = 0; pi < 2; ++pi)
#pragma unroll
      for (int rr = 0; rr < 2; ++rr)
#pragma unroll
        for (int ct = 0; ct < 2; ++ct) acc[pi][rr][ct] = {0.f, 0.f, 0.f, 0.f};

#pragma unroll 1
    for (int kc = 0; kc < 2; ++kc) {
      short8 wf[9][2];
#pragma unroll
      for (int tap = 0; tap < 9; ++tap)
#pragma unroll
        for (int ct = 0; ct < 2; ++ct)
          wf[tap][ct] = __builtin_bit_cast(
              short8, wp4[((tap * 4 + (ow * 2 + ct)) * 2 + kc) * 64 + lane]);
#pragma unroll
      for (int pi = 0; pi < 2; ++pi) {
        int pt = pp * 2 + pi;
#pragma unroll
        for (int ir = 0; ir < 4; ++ir) {
          int ldr = lr + ir;
#pragma unroll
          for (int kx = 0; kx < 3; ++kx) {
            int col = pt * 16 + l15 + kx;
            short8 xf = __builtin_bit_cast(
                short8, lds[(ldr * 66 + col) * 8 + ((kc * 4 + quad) ^ (col & 7))]);
            if (ir <= 2) {
#pragma unroll
              for (int ct = 0; ct < 2; ++ct)
                acc[pi][0][ct] = MFMA_BF16(wf[ir * 3 + kx][ct], xf, acc[pi][0][ct], 0, 0, 0);
            }
            if (ir >= 1) {
#pragma unroll
              for (int ct = 0; ct < 2; ++ct)
                acc[pi][1][ct] = MFMA_BF16(wf[(ir - 1) * 3 + kx][ct], xf, acc[pi][1][ct], 0, 0, 0);
            }
          }
        }
      }
    }
    // epilogue: c2 vertical resample + min, store NCHW fp32
#pragma unroll
    for (int pi = 0; pi < 2; ++pi) {
      int px = colBase + (pp * 2 + pi) * 16 + l15;
#pragma unroll
      for (int rr = 0; rr < 2; ++rr) {
        int y = y0 + lr + rr;
        float sv = s[(b * HH + y) * WW + px];
        float ys = (float)y - sv;
        float fy = floorf(ys);
        float wfr = ys - fy;
        int i0 = (int)fy;
        float lw0 = (i0 + 1 >= 0 && i0 + 1 <= HH) ? 1.0f - wfr : 0.0f;
        float lw1 = (i0 + 2 >= 0 && i0 + 2 <= HH) ? wfr : 0.0f;
        int a0 = min(max(i0 + 1, 0), HH);
        int a1 = min(max(i0 + 2, 0), HH);
#pragma unroll
        for (int ct = 0; ct < 2; ++ct) {
          f32x4 A = acc[pi][rr][ct];
          int ch = (ow * 2 + ct) * 16 + quad * 4;
          U16x4 v0, v1;
          v0.v = *(const uint2*)(c2 + ((size_t)(b * C2R + a0) * WW + px) * CC + ch);
          v1.v = *(const uint2*)(c2 + ((size_t)(b * C2R + a1) * WW + px) * CC + ch);
#pragma unroll
          for (int reg = 0; reg < 4; ++reg) {
            float lower = lw0 * bf2f(v0.h[reg]) + lw1 * bf2f(v1.h[reg]);
            out[((size_t)(b * CC + ch + reg) * HH + y) * WW + px] =
                fminf(A[reg], lower);
          }
        }
      }
    }
  }
}

// ---------------------------------------------------------------------------
extern "C" void kernel_launch(void* const* d_in, const int* in_sizes, int n_in,
                              void* d_out, int out_size, void* d_ws, size_t ws_size,
                              hipStream_t stream) {
  const float* x = (const float*)d_in[0];
  const float* Wt = (const float*)d_in[1];
  float* out = (float*)d_out;

  char* ws = (char*)d_ws;
  float* s = (float*)ws;                                   //   1,048,576 B
  unsigned short* Wp = (unsigned short*)(ws + 1048576);    //      73,728 B
  unsigned short* xn = (unsigned short*)(ws + 1122304);    //  33,816,576 B
  unsigned short* c2 = (unsigned short*)(ws + 34938880);   //  33,685,504 B
                                                           // total 68.6 MB
  k_pack<<<dim3(HH * 2, BB), 256, 0, stream>>>(x, s, xn);
  k_wpack<<<dim3(18), 256, 0, stream>>>(Wt, Wp);
  k_lower<<<dim3(4 * 65, BB), 256, 0, stream>>>(xn, Wp, s, c2);
  k_final<<<dim3(4 * 64, BB), 256, 0, stream>>>(xn, Wp, s, c2, out);
}

// Round 8
// 190.224 us; speedup vs baseline: 1.5788x; 1.0273x over previous
//
#include <hip/hip_runtime.h>
#include <cmath>

constexpr int BB = 4, CC = 64, HH = 256, WW = 256;
constexpr int WP = 258;   // padded width: cols -1..256 stored at col+1
constexpr int C2R = 257;  // c2 rows -1..255 stored at r+1

typedef short short8 __attribute__((ext_vector_type(8)));
typedef float f32x4 __attribute__((ext_vector_type(4)));
#define MFMA_BF16 __builtin_amdgcn_mfma_f32_16x16x32_bf16

union U16x8 { uint4 v; unsigned short h[8]; };
union U16x4 { uint2 v; unsigned short h[4]; };

__device__ inline unsigned short f2bf(float f) {
  unsigned u = __builtin_bit_cast(unsigned, f);
  u += 0x7fffu + ((u >> 16) & 1u);
  return (unsigned short)(u >> 16);
}
__device__ inline unsigned short f2bf_trunc(float f) {
  return (unsigned short)(__builtin_bit_cast(unsigned, f) >> 16);
}
__device__ inline float bf2f(unsigned short h) {
  unsigned u = ((unsigned)h) << 16;
  return __builtin_bit_cast(float, u);
}

// ---------------------------------------------------------------------------
// k_pack: block = half-row (128 px). NCHW fp32 -> col-padded NHWC bf16 +
// fused channel-max -> s. (unchanged, passing)
// ---------------------------------------------------------------------------
__global__ __launch_bounds__(256, 4) void k_pack(const float* __restrict__ x,
                                                 float* __restrict__ s,
                                                 unsigned short* __restrict__ xn) {
  __shared__ float tile[CC * 129];
  __shared__ float pmax[2][128];
  const int t = threadIdx.x;
  const int half = blockIdx.x & 1, y = blockIdx.x >> 1, b = blockIdx.y;
  const int px0 = half * 128;
  const int pxl = t & 127, chb = (t >> 7) * 32;

  const float* base = x + (size_t)b * CC * HH * WW + (size_t)y * WW + px0 + pxl;
  float m = -1e30f;
#pragma unroll 8
  for (int i = 0; i < 32; ++i) {
    float v = base[(size_t)(chb + i) * HH * WW];
    tile[(chb + i) * 129 + pxl] = v;
    m = fmaxf(m, v);
  }
  pmax[t >> 7][pxl] = m;

  uint4* xn4 = (uint4*)xn;
  if (t < 8) {
    int col = half ? (WP - 1) : 0;
    xn4[(((size_t)(b * HH + y) * WP + col) * CC + t * 8) >> 3] =
        make_uint4(0, 0, 0, 0);
  }
  __syncthreads();

  if (t < 128) {
    float mm = fmaxf(pmax[0][t], pmax[1][t]);
    s[(b * HH + y) * WW + px0 + t] = 25.0f / fminf(fmaxf(mm, 1.0f), 50.0f);
  }
#pragma unroll
  for (int g = 0; g < 4; ++g) {
    int px = g * 32 + (t >> 3), c8 = t & 7;
    U16x8 r;
#pragma unroll
    for (int j = 0; j < 8; ++j) r.h[j] = f2bf(tile[(c8 * 8 + j) * 129 + px]);
    xn4[(((size_t)(b * HH + y) * WP + px0 + px + 1) * CC + c8 * 8) >> 3] = r.v;
  }
}

// ---------------------------------------------------------------------------
// k_wpack: W fp32 -> bf16 fragments Wp[tap][mt][kc][lane][8]   (unchanged)
// ---------------------------------------------------------------------------
__global__ __launch_bounds__(256) void k_wpack(const float* __restrict__ Wt,
                                               unsigned short* __restrict__ Wp) {
  int gid = blockIdx.x * 256 + threadIdx.x;  // 4608 total
  int lane = gid & 63, kc = (gid >> 6) & 1, mt = (gid >> 7) & 3, tap = gid >> 9;
  int o = mt * 16 + (lane & 15);
  int kb = kc * 32 + (lane >> 4) * 8;
  int ky = tap / 3, kx = tap % 3;
  U16x8 r;
#pragma unroll
  for (int j = 0; j < 8; ++j)
    r.h[j] = f2bf(Wt[o * 576 + (kb + j) * 9 + ky * 3 + kx]);
  ((uint4*)Wp)[gid] = r.v;
}

// ---------------------------------------------------------------------------
// Conv tile: block = 2 out rows x 64 cols x 64 och.
// LDS: 4 input rows x 66 padded cols x 8 chunks(8ch) uint4 = 33.8 KB
// -> 4 blocks/CU, 2048/2064-block grids = exactly 2 residency rounds.
// Waves: ow = w&1 (32-och half), ch2 = w>>1 (32-col half).
// c2 layout: [b][og=och/4][row+1][px][4och] bf16 -> uint2 per (og,row,px);
// both the k_lower store and the k_final resample load are line-coherent.
// ---------------------------------------------------------------------------
__global__ __launch_bounds__(256, 4) void k_lower(const unsigned short* __restrict__ xn,
                                                  const unsigned short* __restrict__ Wp,
                                                  const float* __restrict__ s,
                                                  unsigned short* __restrict__ c2) {
  __shared__ uint4 lds[2112];
  const int t = threadIdx.x;
  const int ctile = blockIdx.x & 3, tr = blockIdx.x >> 2;
  const int b = blockIdx.y;
  const int r0 = tr * 2 - 1;          // out rows r0, r0+1 in [-1, 256]
  const int colBase = ctile * 64;

  const uint4* xn4 = (const uint4*)xn;
  // staging: 4 x2 rows (r0-1 .. r0+2) blended on the fly, groups of 3 iters
#pragma unroll 1
  for (int g = 0; g < 3; ++g) {
    float w0a[3], w1a[3];
    int o0a[3], o1a[3], la[3];
    bool act[3], va[3];
#pragma unroll
    for (int j = 0; j < 3; ++j) {
      int idx = (g * 3 + j) * 256 + t;
      act[j] = idx < 2112;
      int rr_ = idx / 528, rem = idx % 528;  // 528 = 66 cols * 8 chunks
      int col_ = rem >> 3, ch_ = rem & 7;
      int xrow = r0 - 1 + rr_;  // x2 row, [-2..258]
      va[j] = act[j] && (xrow >= 0) && (xrow < HH);
      la[j] = (rr_ * 66 + col_) * 8 + (ch_ ^ (col_ & 7));
      float sv = 0.0f;
      int pxc = min(max(colBase + col_ - 1, 0), WW - 1);
      if (va[j]) sv = s[(b * HH + min(max(xrow, 0), HH - 1)) * WW + pxc];
      float ys = (float)xrow - sv;
      float fy = floorf(ys);
      float wfr = ys - fy;
      int i0 = (int)fy;
      w0a[j] = (i0 >= 0) ? 1.0f - wfr : 0.0f;
      w1a[j] = (i0 + 1 >= 0) ? wfr : 0.0f;
      int a0 = min(max(i0, 0), HH - 1), a1 = min(max(i0 + 1, 0), HH - 1);
      o0a[j] = ((b * HH + a0) * WP + colBase + col_) * 8 + ch_;
      o1a[j] = ((b * HH + a1) * WP + colBase + col_) * 8 + ch_;
    }
#pragma unroll
    for (int j = 0; j < 3; ++j) {
      if (act[j]) {
        uint4 v = make_uint4(0, 0, 0, 0);
        if (va[j]) {
          U16x8 u0, u1, rr;
          u0.v = xn4[o0a[j]];
          u1.v = xn4[o1a[j]];
#pragma unroll
          for (int k = 0; k < 8; ++k)
            rr.h[k] = f2bf_trunc(w0a[j] * bf2f(u0.h[k]) + w1a[j] * bf2f(u1.h[k]));
          v = rr.v;
        }
        lds[la[j]] = v;
      }
    }
  }

  const int lane = t & 63, w = t >> 6;
  const int ow = w & 1, ch2 = w >> 1;
  const int quad = lane >> 4, l15 = lane & 15;
  const uint4* wp4 = (const uint4*)Wp;
  __syncthreads();

  f32x4 acc[2][2][2];  // [pt][rr][ct]
#pragma unroll
  for (int pt = 0; pt < 2; ++pt)
#pragma unroll
    for (int rr = 0; rr < 2; ++rr)
#pragma unroll
      for (int ct = 0; ct < 2; ++ct) acc[pt][rr][ct] = {0.f, 0.f, 0.f, 0.f};

#pragma unroll 1
  for (int kc = 0; kc < 2; ++kc) {
    short8 wf[9][2];
#pragma unroll
    for (int tap = 0; tap < 9; ++tap)
#pragma unroll
      for (int ct = 0; ct < 2; ++ct)
        wf[tap][ct] = __builtin_bit_cast(
            short8, wp4[((tap * 4 + (ow * 2 + ct)) * 2 + kc) * 64 + lane]);
#pragma unroll
    for (int pt = 0; pt < 2; ++pt) {
#pragma unroll
      for (int ir = 0; ir < 4; ++ir) {
#pragma unroll
        for (int kx = 0; kx < 3; ++kx) {
          int col = ch2 * 32 + pt * 16 + l15 + kx;
          short8 xf = __builtin_bit_cast(
              short8, lds[(ir * 66 + col) * 8 + ((kc * 4 + quad) ^ (col & 7))]);
          if (ir <= 2) {
#pragma unroll
            for (int ct = 0; ct < 2; ++ct)
              acc[pt][0][ct] = MFMA_BF16(wf[ir * 3 + kx][ct], xf, acc[pt][0][ct], 0, 0, 0);
          }
          if (ir >= 1) {
#pragma unroll
            for (int ct = 0; ct < 2; ++ct)
              acc[pt][1][ct] = MFMA_BF16(wf[(ir - 1) * 3 + kx][ct], xf, acc[pt][1][ct], 0, 0, 0);
          }
        }
      }
    }
  }

  uint2* c2u = (uint2*)c2;
#pragma unroll
  for (int pt = 0; pt < 2; ++pt) {
    int px = colBase + ch2 * 32 + pt * 16 + l15;
#pragma unroll
    for (int rr = 0; rr < 2; ++rr) {
      int r = r0 + rr;
      if (r > 255) continue;
#pragma unroll
      for (int ct = 0; ct < 2; ++ct) {
        f32x4 A = acc[pt][rr][ct];
        int og = (ow * 2 + ct) * 4 + quad;
        unsigned short h0 = f2bf(A[0]), h1 = f2bf(A[1]), h2 = f2bf(A[2]), h3 = f2bf(A[3]);
        uint2 val = make_uint2((unsigned)h0 | ((unsigned)h1 << 16),
                               (unsigned)h2 | ((unsigned)h3 << 16));
        c2u[(size_t)((b * 16 + og) * C2R + (r + 1)) * WW + px] = val;
      }
    }
  }
}

// ---------------------------------------------------------------------------
// k_final: out rows y0, y0+1. Same tile; epilogue resamples c2 (uint2 loads
// in the packed layout) + min -> out NCHW fp32.
// ---------------------------------------------------------------------------
__global__ __launch_bounds__(256, 4) void k_final(const unsigned short* __restrict__ xn,
                                                  const unsigned short* __restrict__ Wp,
                                                  const float* __restrict__ s,
                                                  const unsigned short* __restrict__ c2,
                                                  float* __restrict__ out) {
  __shared__ uint4 lds[2112];
  const int t = threadIdx.x;
  const int ctile = blockIdx.x & 3, tr = blockIdx.x >> 2;
  const int b = blockIdx.y;
  const int y0 = tr * 2;
  const int colBase = ctile * 64;

  const uint4* src4 = (const uint4*)xn;
#pragma unroll 1
  for (int i = 0; i < 9; ++i) {
    int idx = i * 256 + t;
    if (idx < 2112) {
      int rr_ = idx / 528, rem = idx % 528;
      int col_ = rem >> 3, ch_ = rem & 7;
      int xrow = y0 - 1 + rr_;  // rows y0-1 .. y0+2
      uint4 v = make_uint4(0, 0, 0, 0);
      if (xrow >= 0 && xrow < HH)
        v = src4[((size_t)(b * HH + xrow) * WP + colBase + col_) * 8 + ch_];
      lds[(rr_ * 66 + col_) * 8 + (ch_ ^ (col_ & 7))] = v;
    }
  }

  const int lane = t & 63, w = t >> 6;
  const int ow = w & 1, ch2 = w >> 1;
  const int quad = lane >> 4, l15 = lane & 15;
  const uint4* wp4 = (const uint4*)Wp;
  __syncthreads();

  f32x4 acc[2][2][2];
#pragma unroll
  for (int pt = 0; pt < 2; ++pt)
#pragma unroll
    for (int rr = 0; rr < 2; ++rr)
#pragma unroll
      for (int ct = 0; ct < 2; ++ct) acc[pt][rr][ct] = {0.f, 0.f, 0.f, 0.f};

#pragma unroll 1
  for (int kc = 0; kc < 2; ++kc) {
    short8 wf[9][2];
#pragma unroll
    for (int tap = 0; tap < 9; ++tap)
#pragma unroll
      for (int ct = 0; ct < 2; ++ct)
        wf[tap][ct] = __builtin_bit_cast(
            short8, wp4[((tap * 4 + (ow * 2 + ct)) * 2 + kc) * 64 + lane]);
#pragma unroll
    for (int pt = 0; pt < 2; ++pt) {
#pragma unroll
      for (int ir = 0; ir < 4; ++ir) {
#pragma unroll
        for (int kx = 0; kx < 3; ++kx) {
          int col = ch2 * 32 + pt * 16 + l15 + kx;
          short8 xf = __builtin_bit_cast(
              short8, lds[(ir * 66 + col) * 8 + ((kc * 4 + quad) ^ (col & 7))]);
          if (ir <= 2) {
#pragma unroll
            for (int ct = 0; ct < 2; ++ct)
              acc[pt][0][ct] = MFMA_BF16(wf[ir * 3 + kx][ct], xf, acc[pt][0][ct], 0, 0, 0);
          }
          if (ir >= 1) {
#pragma unroll
            for (int ct = 0; ct < 2; ++ct)
              acc[pt][1][ct] = MFMA_BF16(wf[(ir - 1) * 3 + kx][ct], xf, acc[pt][1][ct], 0, 0, 0);
          }
        }
      }
    }
  }

  const uint2* c2u = (const uint2*)c2;
#pragma unroll
  for (int pt = 0; pt < 2; ++pt) {
    int px = colBase + ch2 * 32 + pt * 16 + l15;
#pragma unroll
    for (int rr = 0; rr < 2; ++rr) {
      int y = y0 + rr;
      float sv = s[(b * HH + y) * WW + px];
      float ys = (float)y - sv;
      float fy = floorf(ys);
      float wfr = ys - fy;
      int i0 = (int)fy;
      float lw0 = (i0 + 1 >= 0 && i0 + 1 <= HH) ? 1.0f - wfr : 0.0f;
      float lw1 = (i0 + 2 >= 0 && i0 + 2 <= HH) ? wfr : 0.0f;
      int a0 = min(max(i0 + 1, 0), HH);
      int a1 = min(max(i0 + 2, 0), HH);
#pragma unroll
      for (int ct = 0; ct < 2; ++ct) {
        f32x4 A = acc[pt][rr][ct];
        int og = (ow * 2 + ct) * 4 + quad;
        U16x4 v0, v1;
        v0.v = c2u[(size_t)((b * 16 + og) * C2R + a0) * WW + px];
        v1.v = c2u[(size_t)((b * 16 + og) * C2R + a1) * WW + px];
#pragma unroll
        for (int reg = 0; reg < 4; ++reg) {
          float lower = lw0 * bf2f(v0.h[reg]) + lw1 * bf2f(v1.h[reg]);
          out[((size_t)(b * CC + og * 4 + reg) * HH + y) * WW + px] =
              fminf(A[reg], lower);
        }
      }
    }
  }
}

// ---------------------------------------------------------------------------
extern "C" void kernel_launch(void* const* d_in, const int* in_sizes, int n_in,
                              void* d_out, int out_size, void* d_ws, size_t ws_size,
                              hipStream_t stream) {
  const float* x = (const float*)d_in[0];
  const float* Wt = (const float*)d_in[1];
  float* out = (float*)d_out;

  char* ws = (char*)d_ws;
  float* s = (float*)ws;                                   //   1,048,576 B
  unsigned short* Wp = (unsigned short*)(ws + 1048576);    //      73,728 B
  unsigned short* xn = (unsigned short*)(ws + 1122304);    //  33,816,576 B
  unsigned short* c2 = (unsigned short*)(ws + 34938880);   //  33,685,504 B
                                                           // total 68.6 MB
  k_pack<<<dim3(HH * 2, BB), 256, 0, stream>>>(x, s, xn);
  k_wpack<<<dim3(18), 256, 0, stream>>>(Wt, Wp);
  k_lower<<<dim3(4 * 129, BB), 256, 0, stream>>>(xn, Wp, s, c2);
  k_final<<<dim3(4 * 128, BB), 256, 0, stream>>>(xn, Wp, s, c2, out);
}